// Round 8
// baseline (199.398 us; speedup 1.0000x reference)
//
#include <hip/hip_runtime.h>
#include <hip/hip_bf16.h>

#define N1 8192
#define N2 8192
#define CDIM 128
#define HC 60
#define WC 80
#define HIMG 480
#define WIMG 640
#define NPIX (HC * WC)
#define INV_DENOM (1.0f / (8192.0f * 256.0f))
#define RECW 98             // uints per row record: 96 packed hist + S4 + cnt

using bf16x8 = __attribute__((ext_vector_type(8))) short;
using f32x4  = __attribute__((ext_vector_type(4))) float;

__device__ __forceinline__ ushort f2bf(float f) {
    union { float f; unsigned u; } x; x.f = f;
    unsigned u = x.u;
    unsigned r = (u + 0x7FFFu + ((u >> 16) & 1u)) >> 16;
    return (ushort)r;
}
__device__ __forceinline__ float bf2f(unsigned bits) {
    union { unsigned u; float f; } x; x.u = bits << 16; return x.f;
}
__device__ __forceinline__ unsigned key2bits(unsigned k) {
    return k ^ ((k & 0x8000u) ? 0x8000u : 0xFFFFu);
}
__device__ __forceinline__ unsigned bits2key(unsigned h) {
    return h ^ ((h & 0x8000u) ? 0xFFFFu : 0x8000u);
}

// ---------- prep: cvt A, cvt B to bf16 ----------
__global__ void prep_kernel(const float* __restrict__ kp1d,
                            const float* __restrict__ kp2d,
                            ushort* __restrict__ Abf, ushort* __restrict__ Bbf) {
    const int n4 = N1 * CDIM / 4;        // 262144
    int i = blockIdx.x * blockDim.x + threadIdx.x;
    if (i < n4) {
        float4 v = ((const float4*)kp1d)[i];
        ushort4 o;
        o.x = f2bf(v.x); o.y = f2bf(v.y); o.z = f2bf(v.z); o.w = f2bf(v.w);
        ((ushort4*)Abf)[i] = o;
    } else if (i < 2 * n4) {
        int k = i - n4;
        float4 v = ((const float4*)kp2d)[k];
        ushort4 o;
        o.x = f2bf(v.x); o.y = f2bf(v.y); o.z = f2bf(v.z); o.w = f2bf(v.w);
        ((ushort4*)Bbf)[k] = o;
    }
}

// ---------- desc2 transpose with LDS tiling ----------
__global__ void tr_kernel(const float* __restrict__ desc2, float* __restrict__ d2T) {
    __shared__ float tile[32][33];
    const int tx = threadIdx.x, ty = threadIdx.y;      // 32 x 8
    const int p0 = blockIdx.x * 32;                    // pixel tile (4800/32=150)
    const int c0 = blockIdx.y * 32;                    // channel tile (128/32=4)
    #pragma unroll
    for (int k = 0; k < 4; k++) {
        int c = c0 + ty + k * 8;
        tile[ty + k * 8][tx] = desc2[(size_t)c * NPIX + p0 + tx];
    }
    __syncthreads();
    #pragma unroll
    for (int k = 0; k < 4; k++) {
        int p = p0 + ty + k * 8;
        d2T[(size_t)p * CDIM + c0 + tx] = tile[tx][ty + k * 8];
    }
}

// ---------- positive term (unchanged) ----------
__global__ void pos_kernel(const float* __restrict__ wkp1,
                           const float* __restrict__ kp1d,
                           const float* __restrict__ desc2T,
                           float* __restrict__ ploss) {
    const int i = blockIdx.x;
    const int c = threadIdx.x;            // 128 threads = 2 waves
    float y = wkp1[2 * i], x = wkp1[2 * i + 1];
    float py = fminf(fmaxf(y / (float)(HIMG - 1) * (float)(HC - 1), 0.0f), (float)(HC - 1));
    float px = fminf(fmaxf(x / (float)(WIMG - 1) * (float)(WC - 1), 0.0f), (float)(WC - 1));
    int y0 = min(max((int)floorf(py), 0), HC - 2);
    int x0 = min(max((int)floorf(px), 0), WC - 2);
    float wy = py - (float)y0;
    float wx = px - (float)x0;
    const int p00 = y0 * WC + x0;
    float v00 = desc2T[(size_t)p00 * CDIM + c];
    float v01 = desc2T[(size_t)(p00 + 1) * CDIM + c];
    float v10 = desc2T[(size_t)(p00 + WC) * CDIM + c];
    float v11 = desc2T[(size_t)(p00 + WC + 1) * CDIM + c];
    float v = v00 * (1.0f - wy) * (1.0f - wx) + v01 * (1.0f - wy) * wx
            + v10 * wy * (1.0f - wx) + v11 * wy * wx;
    float a = kp1d[(size_t)i * CDIM + c];
    float s2 = v * v, sav = a * v;
    #pragma unroll
    for (int off = 32; off >= 1; off >>= 1) {
        s2  += __shfl_down(s2, off);
        sav += __shfl_down(sav, off);
    }
    __shared__ float p2[2], pav[2];
    int wave = threadIdx.x >> 6, lane = threadIdx.x & 63;
    if (lane == 0) { p2[wave] = s2; pav[wave] = sav; }
    __syncthreads();
    if (threadIdx.x == 0) {
        float nrm = sqrtf(p2[0] + p2[1]);
        float pd = (pav[0] + pav[1]) / fmaxf(nrm, 1e-12f);
        float l = fmaxf(1.0f - pd, 0.0f) * (256.0f / 3.0f);
        ploss[i] = l * INV_DENOM;
    }
}

// ---------- masked GEMM + in-LDS per-row packed histogram (R8) ----------
// R7 post-mortem: mechanism right (WRITE 69->27 MB) but latency-bound: 58.9KB
// LDS -> 2 blocks/CU, and stage->barrier->compute with nothing overlapping
// the ~500cy staging window (MfmaUtil 8%, VALUBusy 52%, Occ 18.5% -- nothing
// saturated). R8: (1) B tile 64 cols (16 KB), 16 its; (2) REGISTER-prefetch
// staging: next tile's 4 global_load_dwordx4 issued before this tile's
// MFMA+epilogue, ds_write after the barrier -- latency hides under ~1000cy of
// compute; (3) kp2 coords staged once (8 KB); (4) LDS ~50 KB -> 3 blocks/CU.
// Histogram/records identical to R7 (proven): packed ushort bins (<=1024 per
// block: no carry), fixed-point ssum/scnt for >32, record stride 98.
__global__ __launch_bounds__(256, 3)
void gemm_kernel(const ushort* __restrict__ A, const ushort* __restrict__ B,
                 const float* __restrict__ wkp1, const float* __restrict__ kp2,
                 unsigned* __restrict__ parts) {
    __shared__ ushort sB[64 * 128];           // 16 KB swizzled B tile
    __shared__ unsigned shist[64 * 96];       // 24 KB packed ushort hist
    __shared__ float s_k[2048];               // 8 KB block's 1024 col coords
    __shared__ unsigned dmy[64];
    __shared__ unsigned ssum[64], scnt[64];
    __shared__ float s_w[128];

    const int t = threadIdx.x;
    const int split = blockIdx.x;             // 0..7
    const int mtile = blockIdx.y;             // 0..127
    const int m0 = mtile * 64;
    const int ncol0 = split * 1024;

    for (int i = t; i < 64 * 96; i += 256) shist[i] = 0u;
    if (t < 64) { ssum[t] = 0u; scnt[t] = 0u; }
    if (t < 128) s_w[t] = wkp1[2 * m0 + t];
    #pragma unroll
    for (int i2 = 0; i2 < 8; i2++)
        s_k[t + 256 * i2] = kp2[2 * ncol0 + t + 256 * i2];

    const int lane = t & 63;
    const int wave = t >> 6;
    const int wm = wave >> 1, wn = wave & 1;
    const int lrow = lane & 15, quad = lane >> 4;

    // A fragments resident in registers for the whole block (32 VGPR)
    bf16x8 afr[4][2];
    #pragma unroll
    for (int kit = 0; kit < 4; kit++)
        #pragma unroll
        for (int mt = 0; mt < 2; mt++)
            afr[kit][mt] = *(const bf16x8*)(A
                + (size_t)(m0 + wm * 32 + mt * 16 + lrow) * CDIM + kit * 32 + quad * 8);

    const float thr = 2.0f * sqrtf(32.0f) + 0.1f;
    const float thr2 = thr * thr;

    // stage slot geometry: uint4 idx = t + 256*i2 (0..1023); col j = idx>>4,
    // slot s = idx&15 holds k-range s*8, stored at s^(j&7) (bank spread).
    const int sj = t >> 4, ss = t & 15;
    const int wslot = (sj * 16 + (ss ^ (sj & 7))) * 8;      // ushort offset

    // prologue: stage tile 0
    uint4 stg[4];
    {
        const uint4* Bg = (const uint4*)(B + (size_t)ncol0 * CDIM);
        #pragma unroll
        for (int i2 = 0; i2 < 4; i2++) stg[i2] = Bg[t + 256 * i2];
        #pragma unroll
        for (int i2 = 0; i2 < 4; i2++)
            *(uint4*)(sB + wslot + i2 * 16 * 128) = stg[i2];   // +16 cols each
    }
    __syncthreads();

    for (int it = 0; it < 16; it++) {
        // issue next tile's loads early (latency hides under MFMA+epilogue)
        if (it < 15) {
            const uint4* Bg = (const uint4*)(B + (size_t)(ncol0 + (it + 1) * 64) * CDIM);
            #pragma unroll
            for (int i2 = 0; i2 < 4; i2++) stg[i2] = Bg[t + 256 * i2];
        }

        f32x4 acc[2][2];
        #pragma unroll
        for (int i = 0; i < 2; i++)
            #pragma unroll
            for (int j = 0; j < 2; j++) acc[i][j] = (f32x4){0.f, 0.f, 0.f, 0.f};

        #pragma unroll
        for (int kit = 0; kit < 4; kit++) {
            bf16x8 bfr[2];
            #pragma unroll
            for (int nt = 0; nt < 2; nt++) {
                int j = wn * 32 + nt * 16 + lrow;
                int slot = (kit * 4 + quad) ^ (j & 7);
                bfr[nt] = *(const bf16x8*)(sB + (j * 16 + slot) * 8);
            }
            #pragma unroll
            for (int mt = 0; mt < 2; mt++)
                #pragma unroll
                for (int nt = 0; nt < 2; nt++)
                    acc[mt][nt] = __builtin_amdgcn_mfma_f32_16x16x32_bf16(
                        afr[kit][mt], bfr[nt], acc[mt][nt], 0, 0, 0);
        }

        float ky[2], kx[2];
        #pragma unroll
        for (int nt = 0; nt < 2; nt++) {
            int jl = it * 64 + wn * 32 + nt * 16 + lrow;
            ky[nt] = s_k[2 * jl]; kx[nt] = s_k[2 * jl + 1];
        }

        #pragma unroll
        for (int mt = 0; mt < 2; mt++) {
            #pragma unroll
            for (int r = 0; r < 4; r++) {
                const int il = wm * 32 + mt * 16 + quad * 4 + r;   // local row
                const float wy = s_w[2 * il], wx = s_w[2 * il + 1];
                unsigned* hrow = &shist[il * 96];
                unsigned hbits[2]; bool hi2[2]; bool anyhi = false;
                #pragma unroll
                for (int nt = 0; nt < 2; nt++) {
                    float dy = wy - ky[nt], dx = wx - kx[nt];
                    float v = acc[mt][nt][r];
                    v = (dy * dy + dx * dx <= thr2) ? v - 5.0f : v;
                    unsigned h = (unsigned)f2bf(v);
                    hbits[nt] = h;
                    unsigned u = h - 0x4141u;
                    unsigned* p = (u < 0xC0u) ? &hrow[u >> 1] : &dmy[lane];
                    atomicAdd(p, 1u << ((u & 1u) * 16u));
                    bool ih = ((u - 0xC0u) < 0x3D80u);      // v > 32, positive
                    hi2[nt] = ih; anyhi |= ih;
                }
                if (__any(anyhi)) {                          // rare (~0.25%)
                    #pragma unroll
                    for (int nt = 0; nt < 2; nt++)
                        if (hi2[nt]) {
                            atomicAdd(&ssum[il], (unsigned)(int)(bf2f(hbits[nt]) * 4.0f));
                            atomicAdd(&scnt[il], 1u);
                        }
                }
            }
        }
        __syncthreads();                      // all waves done reading sB
        if (it < 15) {
            #pragma unroll
            for (int i2 = 0; i2 < 4; i2++)
                *(uint4*)(sB + wslot + i2 * 16 * 128) = stg[i2];
            __syncthreads();
        }
    }

    // write record: 64 rows x [96 packed hist | S4 | cnt], stride RECW=98
    const size_t blockbase = (size_t)(mtile * 8 + split) * 64 * RECW;
    for (int i = t; i < 64 * RECW; i += 256) {
        int row = i / RECW;
        int w = i - row * RECW;
        unsigned val = (w < 96) ? shist[row * 96 + w]
                                : (w == 96 ? ssum[row] : scnt[row]);
        parts[blockbase + i] = val;
    }
}

// ---------- per-row top-256 hinge from merged records (stride 98) ----------
// One wave per row (2048 blocks). Merge 8 packed records (halves <= 8*1024:
// no carry), redistribute via LDS, then the proven suffix-scan /
// threshold-find / f64 per-bin sums (bit-identical to R7). >32 contribution
// = 0.25*S4 - 0.2*nhi, exact fixed point -> deterministic. Fallback (tot<256
// | nhi>255; P~0) recomputes the row from Abf/Bbf.
__global__ __launch_bounds__(256)
void select_kernel(const unsigned* __restrict__ parts,
                   const ushort* __restrict__ A, const ushort* __restrict__ B,
                   const float* __restrict__ wkp1, const float* __restrict__ kp2,
                   float* __restrict__ rloss) {
    const int wave = threadIdx.x >> 6, l = threadIdx.x & 63;
    const int g = blockIdx.x * 4 + wave;          // global row
    const int mtile = g >> 6, rowin = g & 63;

    __shared__ unsigned merged_s[4][192];
    unsigned* merged = merged_s[wave];

    unsigned w0 = 0, w1 = 0, nhi = 0, S4 = 0;
    #pragma unroll
    for (int rg = 0; rg < 8; rg++) {
        const unsigned* rp = parts + ((size_t)(mtile * 8 + rg) * 64 + rowin) * RECW;
        w0 += rp[l];
        if (l < 32) w1 += rp[64 + l];
        S4  += rp[96];
        nhi += rp[97];
    }
    merged[2 * l]     = w0 & 0xFFFFu;
    merged[2 * l + 1] = w0 >> 16;
    if (l < 32) {
        merged[128 + 2 * l] = w1 & 0xFFFFu;
        merged[129 + 2 * l] = w1 >> 16;
    }
    __syncthreads();     // all 4 waves reach this exactly once; none after

    unsigned c0 = merged[l], c1 = merged[64 + l], c2 = merged[128 + l];

    // inclusive suffix-scan across lanes for each 64-bin chunk
    unsigned s0i = c0, s1i = c1, s2i = c2;
    #pragma unroll
    for (int off = 1; off < 64; off <<= 1) {
        unsigned t0 = __shfl_down(s0i, off);
        unsigned t1 = __shfl_down(s1i, off);
        unsigned t2 = __shfl_down(s2i, off);
        if (l + off < 64) { s0i += t0; s1i += t1; s2i += t2; }
    }
    const unsigned T0 = __shfl(s0i, 0), T1 = __shfl(s1i, 0), T2 = __shfl(s2i, 0);
    const unsigned tot = nhi + T0 + T1 + T2;      // count of values > 12.0

    const unsigned Ce0 = nhi + T1 + T2 + (s0i - c0);
    const unsigned Ce1 = nhi + T2 + (s1i - c1);
    const unsigned Ce2 = nhi + (s2i - c2);

    const bool ok = (tot >= 256u) && (nhi <= 255u);

    const float thr = 2.0f * sqrtf(32.0f) + 0.1f;
    const float thr2 = thr * thr;

    unsigned ktb;            // bf16 bits of 256th-largest (attained)
    double s = 0.0;
    int cgt = 0;

    if (ok) {
        unsigned long long m0 = __ballot(Ce0 < 256u);
        unsigned long long m1 = __ballot(Ce1 < 256u);
        unsigned long long m2 = __ballot(Ce2 < 256u);
        int bmin; unsigned cg;
        if (m0) { int fl = __ffsll(m0) - 1; bmin = fl;       cg = __shfl(Ce0, fl); }
        else if (m1) { int fl = __ffsll(m1) - 1; bmin = 64 + fl;  cg = __shfl(Ce1, fl); }
        else { int fl = __ffsll(m2) - 1; bmin = 128 + fl; cg = __shfl(Ce2, fl); }
        ktb = 0x4141u + (unsigned)bmin;
        cgt = (int)cg;
        // per-bin hinge sums: cnt * (f32)(val - 0.2f), exact in f64
        if (l > bmin)       s += (double)c0 * (double)(bf2f(0x4141u + (unsigned)l) - 0.2f);
        if (64 + l > bmin)  s += (double)c1 * (double)(bf2f(0x4141u + 64u + (unsigned)l) - 0.2f);
        if (128 + l > bmin) s += (double)c2 * (double)(bf2f(0x4141u + 128u + (unsigned)l) - 0.2f);
        #pragma unroll
        for (int off = 32; off >= 1; off >>= 1) s += __shfl_down(s, off);
        // >32 values: all above threshold; exact fixed-point sum
        if (l == 0)
            s += 0.25 * (double)S4 - (double)0.2f * (double)nhi;
    } else {
        // ---- exact fallback: recompute the row's dots on the fly (never in
        // practice; >10-sigma events). Scalar-FMA recompute of the bf16 dots.
        int lo = -1, hi = 65535;
        while (hi - lo > 1) {
            unsigned midu = (unsigned)((lo + hi) >> 1);
            int c = 0;
            for (int cc = l; cc < N2; cc += 64) {
                const ushort* ar = A + (size_t)g * CDIM;
                const ushort* br = B + (size_t)cc * CDIM;
                float av = 0.f;
                for (int k = 0; k < CDIM; k++)
                    av = fmaf(bf2f(ar[k]), bf2f(br[k]), av);
                float dy = wkp1[2 * g] - kp2[2 * cc];
                float dx = wkp1[2 * g + 1] - kp2[2 * cc + 1];
                if (dy * dy + dx * dx <= thr2) av -= 5.0f;
                c += (int)(bits2key((unsigned)f2bf(av)) > midu);
            }
            #pragma unroll
            for (int off = 32; off >= 1; off >>= 1) c += __shfl_down(c, off);
            c = __shfl(c, 0);
            if (c >= 256) lo = (int)midu; else hi = (int)midu;
        }
        unsigned kt = (unsigned)hi;
        for (int cc = l; cc < N2; cc += 64) {
            const ushort* ar = A + (size_t)g * CDIM;
            const ushort* br = B + (size_t)cc * CDIM;
            float av = 0.f;
            for (int k = 0; k < CDIM; k++)
                av = fmaf(bf2f(ar[k]), bf2f(br[k]), av);
            float dy = wkp1[2 * g] - kp2[2 * cc];
            float dx = wkp1[2 * g + 1] - kp2[2 * cc + 1];
            if (dy * dy + dx * dx <= thr2) av -= 5.0f;
            unsigned h = (unsigned)f2bf(av);
            if (bits2key(h) > kt) {
                s += (double)fmaxf(bf2f(h) - 0.2f, 0.f);
                cgt++;
            }
        }
        ktb = key2bits(kt);
        #pragma unroll
        for (int off = 32; off >= 1; off >>= 1) {
            s += __shfl_down(s, off);
            cgt += __shfl_down(cgt, off);
        }
    }

    if (l == 0) {
        float vt = bf2f(ktb);
        double S = s + (double)(256 - cgt) * (double)fmaxf(vt - 0.2f, 0.0f);
        rloss[g] = (float)(S * (double)INV_DENOM);
    }
}

// ---------- final reduce: sum 2*N1 floats -> out[0] ----------
__global__ void reduce_kernel(const float* __restrict__ a, float* __restrict__ out) {
    const int t = threadIdx.x;
    float s = 0.f;
    for (int i = t; i < 2 * N1; i += 256) s += a[i];
    #pragma unroll
    for (int off = 32; off >= 1; off >>= 1) s += __shfl_down(s, off);
    __shared__ float ws[4];
    int wave = t >> 6, lane = t & 63;
    if (lane == 0) ws[wave] = s;
    __syncthreads();
    if (t == 0) out[0] = ws[0] + ws[1] + ws[2] + ws[3];
}

extern "C" void kernel_launch(void* const* d_in, const int* in_sizes, int n_in,
                              void* d_out, int out_size, void* d_ws, size_t ws_size,
                              hipStream_t stream) {
    const float* wkp1  = (const float*)d_in[1];
    const float* kp2   = (const float*)d_in[2];
    const float* kp1d  = (const float*)d_in[3];
    const float* kp2d  = (const float*)d_in[4];
    const float* desc2 = (const float*)d_in[5];
    float* out = (float*)d_out;

    ushort*   Abf   = (ushort*)d_ws;                        // 2 MB
    ushort*   Bbf   = Abf + (size_t)N1 * CDIM;              // 2 MB
    float*    loss  = (float*)(Bbf + (size_t)N2 * CDIM);    // 64 KB (pos | rows)
    float*    d2T   = loss + 2 * N1;                        // 2.4 MB
    unsigned* parts = (unsigned*)(d2T + (size_t)NPIX * CDIM); // 25.7 MB records

    int n4 = N1 * CDIM / 4;
    prep_kernel<<<(2 * n4) / 256, 256, 0, stream>>>(kp1d, kp2d, Abf, Bbf);

    tr_kernel<<<dim3(NPIX / 32, CDIM / 32), dim3(32, 8), 0, stream>>>(desc2, d2T);

    pos_kernel<<<N1, 128, 0, stream>>>(wkp1, kp1d, d2T, loss);

    dim3 grid(8, N1 / 64);              // 8 splits x 128 mtiles = 1024 blocks
    gemm_kernel<<<grid, 256, 0, stream>>>(Abf, Bbf, wkp1, kp2, parts);

    select_kernel<<<N1 / 4, 256, 0, stream>>>(parts, Abf, Bbf, wkp1, kp2,
                                              loss + N1);

    reduce_kernel<<<1, 256, 0, stream>>>(loss, out);
}

// Round 9
// 159.631 us; speedup vs baseline: 1.2491x; 1.2491x over previous
//
#include <hip/hip_runtime.h>
#include <hip/hip_bf16.h>

#define N1 8192
#define N2 8192
#define CDIM 128
#define HC 60
#define WC 80
#define HIMG 480
#define WIMG 640
#define NPIX (HC * WC)
#define INV_DENOM (1.0f / (8192.0f * 256.0f))
#define THIBITS 0x4200u     // bf16 bits of 32.0
#define PADK 136            // LDS row stride (128 + 8 ushort): keeps 16B align

using bf16x8 = __attribute__((ext_vector_type(8))) short;
using f32x4  = __attribute__((ext_vector_type(4))) float;

__device__ __forceinline__ ushort f2bf(float f) {
    union { float f; unsigned u; } x; x.f = f;
    unsigned u = x.u;
    unsigned r = (u + 0x7FFFu + ((u >> 16) & 1u)) >> 16;
    return (ushort)r;
}
__device__ __forceinline__ float bf2f(unsigned bits) {
    union { unsigned u; float f; } x; x.u = bits << 16; return x.f;
}
__device__ __forceinline__ unsigned key2bits(unsigned k) {
    return k ^ ((k & 0x8000u) ? 0x8000u : 0xFFFFu);
}
__device__ __forceinline__ unsigned pair2key(unsigned x) {   // fallback only
    return x ^ 0x80008000u ^ (((x >> 15) & 0x00010001u) * 0x7FFFu);
}

// ---------- prep: cvt A, cvt B to bf16 (R9: transpose moved to tr_kernel) ----------
__global__ void prep_kernel(const float* __restrict__ kp1d,
                            const float* __restrict__ kp2d,
                            ushort* __restrict__ Abf, ushort* __restrict__ Bbf) {
    const int n4 = N1 * CDIM / 4;        // 262144
    int i = blockIdx.x * blockDim.x + threadIdx.x;
    if (i < n4) {
        float4 v = ((const float4*)kp1d)[i];
        ushort4 o;
        o.x = f2bf(v.x); o.y = f2bf(v.y); o.z = f2bf(v.z); o.w = f2bf(v.w);
        ((ushort4*)Abf)[i] = o;
    } else if (i < 2 * n4) {
        int k = i - n4;
        float4 v = ((const float4*)kp2d)[k];
        ushort4 o;
        o.x = f2bf(v.x); o.y = f2bf(v.y); o.z = f2bf(v.z); o.w = f2bf(v.w);
        ((ushort4*)Bbf)[k] = o;
    }
}

// ---------- desc2 transpose with LDS tiling (R9: isolated fix) ----------
// R0-R5's prep did this as an integer-divide + 4B scatter at stride 512B
// (one 64B line per 4B store). LDS-tiled version: coalesced reads AND writes.
__global__ void tr_kernel(const float* __restrict__ desc2, float* __restrict__ d2T) {
    __shared__ float tile[32][33];
    const int tx = threadIdx.x, ty = threadIdx.y;      // 32 x 8
    const int p0 = blockIdx.x * 32;                    // pixel tile (4800/32=150)
    const int c0 = blockIdx.y * 32;                    // channel tile (128/32=4)
    #pragma unroll
    for (int k = 0; k < 4; k++) {
        int c = c0 + ty + k * 8;
        tile[ty + k * 8][tx] = desc2[(size_t)c * NPIX + p0 + tx];
    }
    __syncthreads();
    #pragma unroll
    for (int k = 0; k < 4; k++) {
        int p = p0 + ty + k * 8;
        d2T[(size_t)p * CDIM + c0 + tx] = tile[tx][ty + k * 8];
    }
}

// ---------- positive term (R2 verbatim) ----------
__global__ void pos_kernel(const float* __restrict__ wkp1,
                           const float* __restrict__ kp1d,
                           const float* __restrict__ desc2T,
                           float* __restrict__ ploss) {
    const int i = blockIdx.x;
    const int c = threadIdx.x;            // 128 threads = 2 waves
    float y = wkp1[2 * i], x = wkp1[2 * i + 1];
    float py = fminf(fmaxf(y / (float)(HIMG - 1) * (float)(HC - 1), 0.0f), (float)(HC - 1));
    float px = fminf(fmaxf(x / (float)(WIMG - 1) * (float)(WC - 1), 0.0f), (float)(WC - 1));
    int y0 = min(max((int)floorf(py), 0), HC - 2);
    int x0 = min(max((int)floorf(px), 0), WC - 2);
    float wy = py - (float)y0;
    float wx = px - (float)x0;
    const int p00 = y0 * WC + x0;
    float v00 = desc2T[(size_t)p00 * CDIM + c];
    float v01 = desc2T[(size_t)(p00 + 1) * CDIM + c];
    float v10 = desc2T[(size_t)(p00 + WC) * CDIM + c];
    float v11 = desc2T[(size_t)(p00 + WC + 1) * CDIM + c];
    float v = v00 * (1.0f - wy) * (1.0f - wx) + v01 * (1.0f - wy) * wx
            + v10 * wy * (1.0f - wx) + v11 * wy * wx;
    float a = kp1d[(size_t)i * CDIM + c];
    float s2 = v * v, sav = a * v;
    #pragma unroll
    for (int off = 32; off >= 1; off >>= 1) {
        s2  += __shfl_down(s2, off);
        sav += __shfl_down(sav, off);
    }
    __shared__ float p2[2], pav[2];
    int wave = threadIdx.x >> 6, lane = threadIdx.x & 63;
    if (lane == 0) { p2[wave] = s2; pav[wave] = sav; }
    __syncthreads();
    if (threadIdx.x == 0) {
        float nrm = sqrtf(p2[0] + p2[1]);
        float pd = (pav[0] + pav[1]) / fmaxf(nrm, 1e-12f);
        float l = fmaxf(1.0f - pd, 0.0f) * (256.0f / 3.0f);
        ploss[i] = l * INV_DENOM;
    }
}

// ---------- masked GEMM, LDS-staged, packed permuted stores (R2 verbatim) ----------
// R4-R8 post-mortem: every epilogue addition (byte encode, LDS hist, hi-gates)
// cost more than the handoff traffic it saved (172-199us vs this structure's
// 162.9). Pure MFMA + plain ull stores is the measured-best gemm (47.5us).
__global__ __launch_bounds__(256, 2)
void gemm_kernel(const ushort* __restrict__ A, const ushort* __restrict__ B,
                 const float* __restrict__ wkp1, const float* __restrict__ kp2,
                 ushort* __restrict__ dots, int m_off) {
    __shared__ ushort sA[128 * PADK];     // 34 KB
    __shared__ ushort sB[128 * PADK];     // 34 KB
    __shared__ float s_w[256], s_k[256];  // 2 KB coords

    const int t = threadIdx.x;
    const int n0 = blockIdx.x * 128;
    const int m0 = m_off + blockIdx.y * 128;

    s_w[t] = wkp1[2 * m0 + t];
    s_k[t] = kp2[2 * n0 + t];

    {
        const uint4* Ag = (const uint4*)(A + (size_t)m0 * CDIM);
        const uint4* Bg = (const uint4*)(B + (size_t)n0 * CDIM);
        #pragma unroll
        for (int r = 0; r < 8; r++) {
            int g = t + 256 * r;          // uint4 index 0..2047
            int row = g >> 4;
            int k8 = g & 15;
            uint4 va = Ag[g];
            uint4 vb = Bg[g];
            *(uint4*)(sA + row * PADK + k8 * 8) = va;
            *(uint4*)(sB + row * PADK + k8 * 8) = vb;
        }
    }
    __syncthreads();

    const int lane = t & 63;
    const int wave = t >> 6;
    const int wm = wave >> 1, wn = wave & 1;
    const int lrow = lane & 15, quad = lane >> 4;

    f32x4 acc[4][4];
    #pragma unroll
    for (int i = 0; i < 4; i++)
        #pragma unroll
        for (int j = 0; j < 4; j++) acc[i][j] = (f32x4){0.f, 0.f, 0.f, 0.f};

    #pragma unroll
    for (int kit = 0; kit < 4; kit++) {
        const int kk = kit * 32 + quad * 8;
        bf16x8 af[4], bfr[4];
        #pragma unroll
        for (int mt = 0; mt < 4; mt++)
            af[mt] = *(const bf16x8*)(sA + (wm * 64 + mt * 16 + lrow) * PADK + kk);
        #pragma unroll
        for (int nt = 0; nt < 4; nt++)
            bfr[nt] = *(const bf16x8*)(sB + (wn * 64 + nt * 16 + lrow) * PADK + kk);
        #pragma unroll
        for (int mt = 0; mt < 4; mt++)
            #pragma unroll
            for (int nt = 0; nt < 4; nt++)
                acc[mt][nt] = __builtin_amdgcn_mfma_f32_16x16x32_bf16(
                    af[mt], bfr[nt], acc[mt][nt], 0, 0, 0);
    }

    float ky[4], kx[4];
    #pragma unroll
    for (int nt = 0; nt < 4; nt++) {
        int jl = wn * 64 + nt * 16 + lrow;
        ky[nt] = s_k[2 * jl]; kx[nt] = s_k[2 * jl + 1];
    }
    const float thr = 2.0f * sqrtf(32.0f) + 0.1f;
    const float thr2 = thr * thr;
    const size_t colbase = (size_t)(n0 + wn * 64 + lrow * 4);
    #pragma unroll
    for (int mt = 0; mt < 4; mt++) {
        #pragma unroll
        for (int r = 0; r < 4; r++) {
            const int il = wm * 64 + mt * 16 + quad * 4 + r;      // local row
            const int i = m0 + il;
            const float wy = s_w[2 * il], wx = s_w[2 * il + 1];
            unsigned h[4];
            #pragma unroll
            for (int nt = 0; nt < 4; nt++) {
                float dy = wy - ky[nt], dx = wx - kx[nt];
                float v = acc[mt][nt][r];
                if (dy * dy + dx * dx <= thr2) v -= 5.0f;
                h[nt] = (unsigned)f2bf(v);
            }
            unsigned long long pk = (unsigned long long)(h[0] | (h[1] << 16))
                                  | ((unsigned long long)(h[2] | (h[3] << 16)) << 32);
            *(unsigned long long*)(dots + (size_t)(i - m_off) * N2 + colbase) = pk;
        }
    }
}

// ---------- per-row top-256 hinge via 192-bin bf16 HISTOGRAM (R2 verbatim) ----------
__global__ __launch_bounds__(256)
void select_kernel(const ushort* __restrict__ dots, float* __restrict__ rloss,
                   int m_off) {
    const int g = m_off + blockIdx.x;            // global row
    const int t = threadIdx.x;
    const int lane = t & 63;

    __shared__ unsigned hist[193];
    __shared__ unsigned dmy[64];
    __shared__ unsigned hicnt;
    __shared__ ushort hlist[256];

    if (t < 193) hist[t] = 0u;
    if (t == 0) hicnt = 0u;
    __syncthreads();

    const uint4* rp4 = (const uint4*)(dots + (size_t)(g - m_off) * N2);  // 1024 uint4

    // ---- pass 1: histogram build (all 4 waves), 4 uint4 per thread
    #pragma unroll
    for (int j = 0; j < 4; j++) {
        uint4 w = rp4[t + 256 * j];
        unsigned xs[4] = {w.x, w.y, w.z, w.w};
        bool anyhi = false;
        #pragma unroll
        for (int q = 0; q < 4; q++) {
            unsigned lo = xs[q] & 0xFFFFu, hh = xs[q] >> 16;
            unsigned u0 = lo - 0x4141u, u1 = hh - 0x4141u;   // candidate iff < 0x3EBF
            unsigned b0 = min(u0, 192u), b1 = min(u1, 192u);
            unsigned* p0 = (u0 < 0x3EBFu) ? &hist[b0] : &dmy[lane];
            unsigned* p1 = (u1 < 0x3EBFu) ? &hist[b1] : &dmy[lane];
            atomicAdd(p0, 1u);
            atomicAdd(p1, 1u);
            anyhi |= ((u0 - 0xC0u) < 0x3DFFu) | ((u1 - 0xC0u) < 0x3DFFu);
        }
        if (__any(anyhi)) {                       // rare: values > 32.0
            #pragma unroll
            for (int q = 0; q < 4; q++) {
                unsigned lo = xs[q] & 0xFFFFu, hh = xs[q] >> 16;
                unsigned u0 = lo - 0x4141u, u1 = hh - 0x4141u;
                if ((u0 - 0xC0u) < 0x3DFFu) {
                    unsigned id = atomicAdd(&hicnt, 1u);
                    if (id < 255u) hlist[id] = (ushort)lo;
                }
                if ((u1 - 0xC0u) < 0x3DFFu) {
                    unsigned id = atomicAdd(&hicnt, 1u);
                    if (id < 255u) hlist[id] = (ushort)hh;
                }
            }
        }
    }
    __syncthreads();
    if (t >= 64) return;                          // wave0 selects; no barriers follow

    const int l = lane;
    unsigned c0 = hist[l], c1 = hist[64 + l], c2 = hist[128 + l];
    const unsigned nhi = hist[192];

    // inclusive suffix-scan across lanes for each 64-bin chunk
    unsigned s0i = c0, s1i = c1, s2i = c2;
    #pragma unroll
    for (int off = 1; off < 64; off <<= 1) {
        unsigned t0 = __shfl_down(s0i, off);
        unsigned t1 = __shfl_down(s1i, off);
        unsigned t2 = __shfl_down(s2i, off);
        if (l + off < 64) { s0i += t0; s1i += t1; s2i += t2; }
    }
    const unsigned T0 = __shfl(s0i, 0), T1 = __shfl(s1i, 0), T2 = __shfl(s2i, 0);
    const unsigned tot = nhi + T0 + T1 + T2;      // count of values > 12.0 (=totLow)

    // count of values STRICTLY greater than this lane's bin value
    const unsigned Ce0 = nhi + T1 + T2 + (s0i - c0);
    const unsigned Ce1 = nhi + T2 + (s1i - c1);
    const unsigned Ce2 = nhi + (s2i - c2);

    const bool ok = (tot >= 256u) && (nhi <= 255u);

    unsigned ktb;            // bf16 bits of 256th-largest (attained)
    double s = 0.0;
    int cgt = 0;

    if (ok) {
        unsigned long long m0 = __ballot(Ce0 < 256u);
        unsigned long long m1 = __ballot(Ce1 < 256u);
        unsigned long long m2 = __ballot(Ce2 < 256u);
        int bmin; unsigned cg;
        if (m0) { int fl = __ffsll((unsigned long long)m0) - 1; bmin = fl;       cg = __shfl(Ce0, fl); }
        else if (m1) { int fl = __ffsll((unsigned long long)m1) - 1; bmin = 64 + fl;  cg = __shfl(Ce1, fl); }
        else { int fl = __ffsll((unsigned long long)m2) - 1; bmin = 128 + fl; cg = __shfl(Ce2, fl); }
        ktb = 0x4141u + (unsigned)bmin;
        cgt = (int)cg;
        // per-bin hinge sums: cnt * (f32)(val - 0.2f), exact in f64
        if (l > bmin)       s += (double)c0 * (double)(bf2f(0x4141u + (unsigned)l) - 0.2f);
        if (64 + l > bmin)  s += (double)c1 * (double)(bf2f(0x4141u + 64u + (unsigned)l) - 0.2f);
        if (128 + l > bmin) s += (double)c2 * (double)(bf2f(0x4141u + 128u + (unsigned)l) - 0.2f);
        // values > 32.0 (all above threshold; counted inside Ce via nhi)
        for (unsigned p = (unsigned)l; p < nhi; p += 64u)
            s += (double)(bf2f(hlist[p]) - 0.2f);
        // fold per-lane f64 partials
        #pragma unroll
        for (int off = 32; off >= 1; off >>= 1) s += __shfl_down(s, off);
    } else {
        // ---- exact fallback: full-range key-domain bisect from global (full row)
        int lo = -1, hi = 65535;
        while (hi - lo > 1) {
            unsigned midu = (unsigned)((lo + hi) >> 1);
            unsigned midhi = (midu << 16) | 0xFFFFu;
            int c = 0;
            for (int j = 0; j < 16; j++) {
                uint4 w = rp4[l + 64 * j];
                unsigned xs[4] = {w.x, w.y, w.z, w.w};
                #pragma unroll
                for (int u = 0; u < 4; u++) {
                    unsigned kk = pair2key(xs[u]);
                    c += (int)((kk & 0xFFFFu) > midu) + (int)(kk > midhi);
                }
            }
            #pragma unroll
            for (int off = 32; off >= 1; off >>= 1) c += __shfl_down(c, off);
            c = __shfl(c, 0);
            if (c >= 256) lo = (int)midu; else hi = (int)midu;
        }
        unsigned kt = (unsigned)hi;
        const unsigned kthi = (kt << 16) | 0xFFFFu;
        for (int j = 0; j < 16; j++) {
            uint4 w = rp4[l + 64 * j];
            unsigned xs[4] = {w.x, w.y, w.z, w.w};
            #pragma unroll
            for (int u = 0; u < 4; u++) {
                unsigned kk = pair2key(xs[u]);
                unsigned lowk = kk & 0xFFFFu, highk = kk >> 16;
                if (lowk > kt) { s += (double)fmaxf(bf2f(key2bits(lowk))  - 0.2f, 0.f); cgt++; }
                if (kk > kthi) { s += (double)fmaxf(bf2f(key2bits(highk)) - 0.2f, 0.f); cgt++; }
            }
        }
        ktb = key2bits(kt);
        #pragma unroll
        for (int off = 32; off >= 1; off >>= 1) {
            s += __shfl_down(s, off);
            cgt += __shfl_down(cgt, off);
        }
    }

    if (l == 0) {
        float vt = bf2f(ktb);
        double S = s + (double)(256 - cgt) * (double)fmaxf(vt - 0.2f, 0.0f);
        rloss[g] = (float)(S * (double)INV_DENOM);
    }
}

// ---------- final reduce: sum 2*N1 floats -> out[0] ----------
__global__ void reduce_kernel(const float* __restrict__ a, float* __restrict__ out) {
    const int t = threadIdx.x;
    float s = 0.f;
    for (int i = t; i < 2 * N1; i += 256) s += a[i];
    #pragma unroll
    for (int off = 32; off >= 1; off >>= 1) s += __shfl_down(s, off);
    __shared__ float ws[4];
    int wave = t >> 6, lane = t & 63;
    if (lane == 0) ws[wave] = s;
    __syncthreads();
    if (t == 0) out[0] = ws[0] + ws[1] + ws[2] + ws[3];
}

extern "C" void kernel_launch(void* const* d_in, const int* in_sizes, int n_in,
                              void* d_out, int out_size, void* d_ws, size_t ws_size,
                              hipStream_t stream) {
    const float* wkp1  = (const float*)d_in[1];
    const float* kp2   = (const float*)d_in[2];
    const float* kp1d  = (const float*)d_in[3];
    const float* kp2d  = (const float*)d_in[4];
    const float* desc2 = (const float*)d_in[5];
    float* out = (float*)d_out;

    ushort* Abf   = (ushort*)d_ws;                         // 2 MB
    ushort* Bbf   = Abf + (size_t)N1 * CDIM;               // 2 MB
    float*  loss  = (float*)(Bbf + (size_t)N2 * CDIM);     // 64 KB (pos | rows)
    float*  d2T   = loss + 2 * N1;                         // 2.4 MB
    ushort* dots  = (ushort*)(d2T + (size_t)NPIX * CDIM);  // chunked dots

    size_t head_bytes = (size_t)(N1 + N2) * CDIM * sizeof(ushort)
                      + 2 * N1 * sizeof(float)
                      + (size_t)NPIX * CDIM * sizeof(float);
    size_t avail = (ws_size > head_bytes) ? (ws_size - head_bytes) : 0;
    long rows_chunk = (long)(avail / ((size_t)N2 * sizeof(ushort)));
    rows_chunk = (rows_chunk / 128) * 128;
    if (rows_chunk > N1) rows_chunk = N1;
    if (rows_chunk < 128) rows_chunk = 128;      // requires ws >= ~9 MB

    int n4 = N1 * CDIM / 4;
    prep_kernel<<<(2 * n4) / 256, 256, 0, stream>>>(kp1d, kp2d, Abf, Bbf);

    tr_kernel<<<dim3(NPIX / 32, CDIM / 32), dim3(32, 8), 0, stream>>>(desc2, d2T);

    pos_kernel<<<N1, 128, 0, stream>>>(wkp1, kp1d, d2T, loss);

    for (int r0 = 0; r0 < N1; r0 += (int)rows_chunk) {
        int rows = (int)((N1 - r0 < rows_chunk) ? (N1 - r0) : rows_chunk);
        dim3 grid(N2 / 128, rows / 128);
        gemm_kernel<<<grid, 256, 0, stream>>>(Abf, Bbf, wkp1, kp2, dots, r0);
        select_kernel<<<rows, 256, 0, stream>>>(dots, loss + N1, r0);
    }

    reduce_kernel<<<1, 256, 0, stream>>>(loss, out);
}